// Round 1
// baseline (957.202 us; speedup 1.0000x reference)
//
#include <hip/hip_runtime.h>
#include <hip/hip_bf16.h>
#include <math.h>

// GATv2 3-layer GNN, MI355X. CSR-by-dst build + wave-per-node softmax/aggregate.

__device__ __forceinline__ float lrelu(float x) { return x > 0.f ? x : 0.2f * x; }
__device__ __forceinline__ float elu1(float x) { return x > 0.f ? x : expm1f(x); }

// ---------------- CSR build ----------------
__global__ void k_zero_i32(int* __restrict__ p, int n) {
    int i = blockIdx.x * blockDim.x + threadIdx.x;
    if (i < n) p[i] = 0;
}

// deg[dst]++ over E real edges + N self loops
__global__ void k_hist(const int* __restrict__ ei, int E, int N, int* __restrict__ deg) {
    int e = blockIdx.x * blockDim.x + threadIdx.x;
    int Etot = E + N;
    if (e >= Etot) return;
    int d = (e < E) ? ei[E + e] : (e - E);
    atomicAdd(&deg[d], 1);
}

// single-block hierarchical exclusive scan: row_off[0..n], cursor = copy
__global__ void __launch_bounds__(1024) k_scan(const int* __restrict__ deg, int n,
                                               int* __restrict__ row_off, int* __restrict__ cursor) {
    __shared__ int wsum[16];
    __shared__ int sbase;
    int tid = threadIdx.x;
    int lane = tid & 63, w = tid >> 6;
    if (tid == 0) sbase = 0;
    __syncthreads();
    for (int start = 0; start < n; start += 1024) {
        int i = start + tid;
        int v = (i < n) ? deg[i] : 0;
        int s = v;
        #pragma unroll
        for (int d = 1; d < 64; d <<= 1) {
            int t = __shfl_up(s, d, 64);
            if (lane >= d) s += t;
        }
        if (lane == 63) wsum[w] = s;
        __syncthreads();                       // wsum visible
        int wbase = 0;
        for (int k = 0; k < w; k++) wbase += wsum[k];
        int excl = sbase + wbase + (s - v);
        if (i < n) { row_off[i] = excl; cursor[i] = excl; }
        __syncthreads();                       // all reads of sbase done
        if (tid == 1023) sbase = excl + v;     // base += chunk total
        __syncthreads();                       // new base visible
    }
    if (tid == 0) row_off[n] = sbase;
}

__global__ void k_scatter(const int* __restrict__ ei, int E, int N,
                          int* __restrict__ cursor,
                          int* __restrict__ csr_src, int* __restrict__ csr_dst) {
    int e = blockIdx.x * blockDim.x + threadIdx.x;
    int Etot = E + N;
    if (e >= Etot) return;
    int s, d;
    if (e < E) { s = ei[e]; d = ei[E + e]; } else { s = e - E; d = e - E; }
    int p = atomicAdd(&cursor[d], 1);
    csr_src[p] = s;
    csr_dst[p] = d;
}

// ---------------- dense linear: xl = x@Wl+bl, xr = x@Wr+br ----------------
// block = 2*M threads, 8 nodes per block staged in LDS
__global__ void k_linear(const float* __restrict__ x, int N, int K, int M,
                         const float* __restrict__ Wl, const float* __restrict__ bl,
                         const float* __restrict__ Wr, const float* __restrict__ br,
                         float* __restrict__ xl, float* __restrict__ xr) {
    extern __shared__ float xs[];  // [8][K]
    const int BN = 8;
    int tid = threadIdx.x;
    int base = blockIdx.x * BN;
    for (int idx = tid; idx < BN * K; idx += blockDim.x) {
        int j = idx / K, k = idx - j * K;
        int node = base + j;
        xs[idx] = (node < N) ? x[(size_t)node * K + k] : 0.f;
    }
    __syncthreads();
    bool right = (tid >= M);
    int col = right ? tid - M : tid;
    const float* W = right ? Wr : Wl;
    float b = right ? br[col] : bl[col];
    float acc[BN];
    #pragma unroll
    for (int j = 0; j < BN; j++) acc[j] = 0.f;
    for (int k = 0; k < K; k++) {
        float wv = W[(size_t)k * M + col];
        #pragma unroll
        for (int j = 0; j < BN; j++) acc[j] += xs[j * K + k] * wv;
    }
    float* out = right ? xr : xl;
    #pragma unroll
    for (int j = 0; j < BN; j++) {
        int node = base + j;
        if (node < N) out[(size_t)node * M + col] = acc[j] + b;
    }
}

// ---------------- per-edge attention scores ----------------
// HC = H*C total feature width, lane-group of HC/8 threads per CSR position
template <int HC, int C, int H>
__global__ void k_score(const int* __restrict__ csr_src, const int* __restrict__ csr_dst,
                        const float* __restrict__ xl, const float* __restrict__ xr,
                        const float* __restrict__ att, float* __restrict__ score, int Etot) {
    constexpr int LANES = HC / 8;   // threads per position (16 or 4)
    constexpr int PERH = C / 8;     // lanes per head (8 or 4)
    int gid = blockIdx.x * blockDim.x + threadIdx.x;
    int p = gid / LANES;
    int j = gid - p * LANES;
    if (p >= Etot) return;
    int s = csr_src[p], d = csr_dst[p];
    const float4* a = (const float4*)(xl + (size_t)s * HC + j * 8);
    const float4* b = (const float4*)(xr + (size_t)d * HC + j * 8);
    const float4* t = (const float4*)(att + j * 8);
    float4 a0 = a[0], a1 = a[1], b0 = b[0], b1 = b[1], t0 = t[0], t1 = t[1];
    float part =
        lrelu(a0.x + b0.x) * t0.x + lrelu(a0.y + b0.y) * t0.y +
        lrelu(a0.z + b0.z) * t0.z + lrelu(a0.w + b0.w) * t0.w +
        lrelu(a1.x + b1.x) * t1.x + lrelu(a1.y + b1.y) * t1.y +
        lrelu(a1.z + b1.z) * t1.z + lrelu(a1.w + b1.w) * t1.w;
    #pragma unroll
    for (int m = 1; m < PERH; m <<= 1) part += __shfl_xor(part, m, 64);
    if ((j & (PERH - 1)) == 0) {
        int h = j / PERH;
        score[(size_t)p * H + h] = part;
    }
}

// ---------------- wave-per-dst softmax + aggregate + bias + elu ----------------
template <int HC, int C, int H>
__global__ void k_agg(const int* __restrict__ row_off, const int* __restrict__ csr_src,
                      const float* __restrict__ score, const float* __restrict__ xl,
                      const float* __restrict__ bias, float* __restrict__ hout, int N) {
    int wid = (blockIdx.x * blockDim.x + threadIdx.x) >> 6;  // dst node
    int lane = threadIdx.x & 63;
    if (wid >= N) return;
    int p0 = row_off[wid], p1 = row_off[wid + 1];
    // phase 1: per-head max over incoming edges (lane-parallel then wave reduce)
    float mx[H];
    #pragma unroll
    for (int h = 0; h < H; h++) mx[h] = -INFINITY;
    for (int p = p0 + lane; p < p1; p += 64) {
        #pragma unroll
        for (int h = 0; h < H; h++) mx[h] = fmaxf(mx[h], score[(size_t)p * H + h]);
    }
    #pragma unroll
    for (int h = 0; h < H; h++)
        #pragma unroll
        for (int m = 1; m < 64; m <<= 1) mx[h] = fmaxf(mx[h], __shfl_xor(mx[h], m, 64));
    // phase 2: serial over edges, lanes own output columns
    constexpr int EPL = (HC + 63) / 64;
    float acc[EPL];
    float den[H];
    #pragma unroll
    for (int q = 0; q < EPL; q++) acc[q] = 0.f;
    #pragma unroll
    for (int h = 0; h < H; h++) den[h] = 0.f;
    for (int p = p0; p < p1; p++) {
        float ex[H];
        #pragma unroll
        for (int h = 0; h < H; h++) {
            ex[h] = expf(score[(size_t)p * H + h] - mx[h]);
            den[h] += ex[h];
        }
        int s = csr_src[p];
        #pragma unroll
        for (int q = 0; q < EPL; q++) {
            int c = lane + q * 64;
            if (c < HC) acc[q] += ex[c / C] * xl[(size_t)s * HC + c];
        }
    }
    #pragma unroll
    for (int q = 0; q < EPL; q++) {
        int c = lane + q * 64;
        if (c < HC) {
            float v = acc[q] / (den[c / C] + 1e-16f) + bias[c];
            hout[(size_t)wid * HC + c] = elu1(v);
        }
    }
}

// ---------------- graph pooling: mean | max over sorted batch ----------------
__global__ void k_pool(const float* __restrict__ h, const int* __restrict__ batch,
                       int N, float* __restrict__ out) {
    int g = blockIdx.x;
    // lower_bound(batch, g) / lower_bound(batch, g+1)
    int lo = 0, hi = N;
    while (lo < hi) { int mid = (lo + hi) >> 1; if (batch[mid] < g) lo = mid + 1; else hi = mid; }
    int start = lo;
    lo = start; hi = N;
    while (lo < hi) { int mid = (lo + hi) >> 1; if (batch[mid] < g + 1) lo = mid + 1; else hi = mid; }
    int end = lo;

    int tid = threadIdx.x;            // 256 threads = 8 rows x 32 cols
    int col = tid & 31, row = tid >> 5;
    float sum = 0.f, mx = -INFINITY;
    for (int i = start + row; i < end; i += 8) {
        float v = h[(size_t)i * 32 + col];
        sum += v;
        mx = fmaxf(mx, v);
    }
    __shared__ float ssum[8][32], smx[8][32];
    ssum[row][col] = sum;
    smx[row][col] = mx;
    __syncthreads();
    if (tid < 32) {
        float s = 0.f, m = -INFINITY;
        #pragma unroll
        for (int r = 0; r < 8; r++) { s += ssum[r][tid]; m = fmaxf(m, smx[r][tid]); }
        int cnt = end - start;
        out[g * 64 + tid] = s / (float)cnt;
        out[g * 64 + 32 + tid] = m;
    }
}

extern "C" void kernel_launch(void* const* d_in, const int* in_sizes, int n_in,
                              void* d_out, int out_size, void* d_ws, size_t ws_size,
                              hipStream_t stream) {
    const float* x      = (const float*)d_in[0];
    const int*   ei     = (const int*)d_in[1];
    const int*   batch  = (const int*)d_in[2];
    const float* Wl1 = (const float*)d_in[3],  *bl1 = (const float*)d_in[4];
    const float* Wr1 = (const float*)d_in[5],  *br1 = (const float*)d_in[6];
    const float* att1= (const float*)d_in[7],  *b1  = (const float*)d_in[8];
    const float* Wl2 = (const float*)d_in[9],  *bl2 = (const float*)d_in[10];
    const float* Wr2 = (const float*)d_in[11], *br2 = (const float*)d_in[12];
    const float* att2= (const float*)d_in[13], *b2  = (const float*)d_in[14];
    const float* Wl3 = (const float*)d_in[15], *bl3 = (const float*)d_in[16];
    const float* Wr3 = (const float*)d_in[17], *br3 = (const float*)d_in[18];
    const float* att3= (const float*)d_in[19], *b3  = (const float*)d_in[20];

    int N = in_sizes[0] / 8;
    int E = in_sizes[1] / 2;
    int G = out_size / 64;
    int Etot = E + N;

    // workspace carve-out (256B aligned)
    char* w = (char*)d_ws;
    auto carve = [&](size_t bytes) {
        void* p = (void*)w;
        w += (bytes + 255) & ~(size_t)255;
        return p;
    };
    int*   deg     = (int*)carve((size_t)N * 4);
    int*   row_off = (int*)carve((size_t)(N + 1) * 4);
    int*   cursor  = (int*)carve((size_t)N * 4);
    int*   csr_src = (int*)carve((size_t)Etot * 4);
    int*   csr_dst = (int*)carve((size_t)Etot * 4);
    float* score   = (float*)carve((size_t)Etot * 2 * 4);
    float* bufA    = (float*)carve((size_t)N * 128 * 4);  // xl
    float* bufB    = (float*)carve((size_t)N * 128 * 4);  // xr / h2 / h3
    float* bufC    = (float*)carve((size_t)N * 128 * 4);  // h1 / xr3
    (void)ws_size; (void)n_in; (void)G;

    // ---- CSR by dst (incl. self loops) ----
    k_zero_i32<<<(N + 255) / 256, 256, 0, stream>>>(deg, N);
    k_hist<<<(Etot + 255) / 256, 256, 0, stream>>>(ei, E, N, deg);
    k_scan<<<1, 1024, 0, stream>>>(deg, N, row_off, cursor);
    k_scatter<<<(Etot + 255) / 256, 256, 0, stream>>>(ei, E, N, cursor, csr_src, csr_dst);

    int blkLin = 0, grdLin = (N + 7) / 8;

    // ---- Layer 1: K=8 -> 128 (H=2,C=64). xl=bufA xr=bufB h1=bufC ----
    blkLin = 256;
    k_linear<<<grdLin, blkLin, 8 * 8 * 4, stream>>>(x, N, 8, 128, Wl1, bl1, Wr1, br1, bufA, bufB);
    k_score<128, 64, 2><<<(int)(((size_t)Etot * 16 + 255) / 256), 256, 0, stream>>>(
        csr_src, csr_dst, bufA, bufB, att1, score, Etot);
    k_agg<128, 64, 2><<<(int)(((size_t)N * 64 + 255) / 256), 256, 0, stream>>>(
        row_off, csr_src, score, bufA, b1, bufC, N);

    // ---- Layer 2: 128 -> 128. in=bufC, xl=bufA xr=bufB, h2=bufB (agg never reads xr) ----
    k_linear<<<grdLin, blkLin, 8 * 128 * 4, stream>>>(bufC, N, 128, 128, Wl2, bl2, Wr2, br2, bufA, bufB);
    k_score<128, 64, 2><<<(int)(((size_t)Etot * 16 + 255) / 256), 256, 0, stream>>>(
        csr_src, csr_dst, bufA, bufB, att2, score, Etot);
    k_agg<128, 64, 2><<<(int)(((size_t)N * 64 + 255) / 256), 256, 0, stream>>>(
        row_off, csr_src, score, bufA, b2, bufB, N);

    // ---- Layer 3: 128 -> 32 (H=1,C=32). in=bufB, xl=bufA xr=bufC, h3=bufB ----
    blkLin = 64;
    k_linear<<<grdLin, blkLin, 8 * 128 * 4, stream>>>(bufB, N, 128, 32, Wl3, bl3, Wr3, br3, bufA, bufC);
    k_score<32, 32, 1><<<(int)(((size_t)Etot * 4 + 255) / 256), 256, 0, stream>>>(
        csr_src, csr_dst, bufA, bufC, att3, score, Etot);
    k_agg<32, 32, 1><<<(int)(((size_t)N * 64 + 255) / 256), 256, 0, stream>>>(
        row_off, csr_src, score, bufA, b3, bufB, N);

    // ---- pooling ----
    k_pool<<<G, 256, 0, stream>>>(bufB, batch, N, (float*)d_out);
}

// Round 2
// 691.475 us; speedup vs baseline: 1.3843x; 1.3843x over previous
//
#include <hip/hip_runtime.h>
#include <hip/hip_bf16.h>
#include <math.h>

// GATv2 3-layer GNN, MI355X. CSR-by-dst + fused online-softmax aggregation.

__device__ __forceinline__ float lrelu(float x) { return x > 0.f ? x : 0.2f * x; }
__device__ __forceinline__ float elu1(float x) { return x > 0.f ? x : expm1f(x); }

// ---------------- CSR build ----------------
__global__ void k_zero_i32(int* __restrict__ p, int n) {
    int i = blockIdx.x * blockDim.x + threadIdx.x;
    if (i < n) p[i] = 0;
}

__global__ void k_hist(const int* __restrict__ ei, int E, int N, int* __restrict__ deg) {
    int e = blockIdx.x * blockDim.x + threadIdx.x;
    int Etot = E + N;
    if (e >= Etot) return;
    int d = (e < E) ? ei[E + e] : (e - E);
    atomicAdd(&deg[d], 1);
}

__global__ void __launch_bounds__(1024) k_scan(const int* __restrict__ deg, int n,
                                               int* __restrict__ row_off, int* __restrict__ cursor) {
    __shared__ int wsum[16];
    __shared__ int sbase;
    int tid = threadIdx.x;
    int lane = tid & 63, w = tid >> 6;
    if (tid == 0) sbase = 0;
    __syncthreads();
    for (int start = 0; start < n; start += 1024) {
        int i = start + tid;
        int v = (i < n) ? deg[i] : 0;
        int s = v;
        #pragma unroll
        for (int d = 1; d < 64; d <<= 1) {
            int t = __shfl_up(s, d, 64);
            if (lane >= d) s += t;
        }
        if (lane == 63) wsum[w] = s;
        __syncthreads();
        int wbase = 0;
        for (int k = 0; k < w; k++) wbase += wsum[k];
        int excl = sbase + wbase + (s - v);
        if (i < n) { row_off[i] = excl; cursor[i] = excl; }
        __syncthreads();
        if (tid == 1023) sbase = excl + v;
        __syncthreads();
    }
    if (tid == 0) row_off[n] = sbase;
}

__global__ void k_scatter(const int* __restrict__ ei, int E, int N,
                          int* __restrict__ cursor,
                          int* __restrict__ csr_src) {
    int e = blockIdx.x * blockDim.x + threadIdx.x;
    int Etot = E + N;
    if (e >= Etot) return;
    int s, d;
    if (e < E) { s = ei[e]; d = ei[E + e]; } else { s = e - E; d = e - E; }
    int p = atomicAdd(&cursor[d], 1);
    csr_src[p] = s;
}

// ---------------- dense linear: xl = x@Wl+bl, xr = x@Wr+br ----------------
__global__ void k_linear(const float* __restrict__ x, int N, int K, int M,
                         const float* __restrict__ Wl, const float* __restrict__ bl,
                         const float* __restrict__ Wr, const float* __restrict__ br,
                         float* __restrict__ xl, float* __restrict__ xr) {
    extern __shared__ float xs[];  // [8][K]
    const int BN = 8;
    int tid = threadIdx.x;
    int base = blockIdx.x * BN;
    for (int idx = tid; idx < BN * K; idx += blockDim.x) {
        int j = idx / K, k = idx - j * K;
        int node = base + j;
        xs[idx] = (node < N) ? x[(size_t)node * K + k] : 0.f;
    }
    __syncthreads();
    bool right = (tid >= M);
    int col = right ? tid - M : tid;
    const float* W = right ? Wr : Wl;
    float b = right ? br[col] : bl[col];
    float acc[BN];
    #pragma unroll
    for (int j = 0; j < BN; j++) acc[j] = 0.f;
    for (int k = 0; k < K; k++) {
        float wv = W[(size_t)k * M + col];
        #pragma unroll
        for (int j = 0; j < BN; j++) acc[j] += xs[j * K + k] * wv;
    }
    float* out = right ? xr : xl;
    #pragma unroll
    for (int j = 0; j < BN; j++) {
        int node = base + j;
        if (node < N) out[(size_t)node * M + col] = acc[j] + b;
    }
}

// ---------------- fused online-softmax attention + aggregate ----------------
// wave per dst node; 4 edge-slots x 16 lanes; CPL cols per lane.
template <int CPL>
__device__ __forceinline__ void loadrow(const float* __restrict__ p, float* v) {
    if constexpr (CPL == 8) {
        float4 a = ((const float4*)p)[0];
        float4 b = ((const float4*)p)[1];
        v[0] = a.x; v[1] = a.y; v[2] = a.z; v[3] = a.w;
        v[4] = b.x; v[5] = b.y; v[6] = b.z; v[7] = b.w;
    } else {
        float2 a = ((const float2*)p)[0];
        v[0] = a.x; v[1] = a.y;
    }
}

template <int HC, int C>
__global__ void k_fused(const int* __restrict__ row_off, const int* __restrict__ csr_src,
                        const float* __restrict__ xl, const float* __restrict__ xr,
                        const float* __restrict__ att, const float* __restrict__ bias,
                        float* __restrict__ hout, int N) {
    constexpr int CPL = HC / 16;          // cols per lane: 8 (HC=128) or 2 (HC=32)
    constexpr int GROUP = (16 * C) / HC;  // lanes per head within a slot: 8 or 16
    int wid = (blockIdx.x * blockDim.x + threadIdx.x) >> 6;
    int lane = threadIdx.x & 63;
    if (wid >= N) return;
    int slot = lane >> 4;     // 0..3
    int j = lane & 15;        // lane within slot
    int c0 = j * CPL;

    int p0 = row_off[wid], p1 = row_off[wid + 1];

    float xrv[CPL], attv[CPL];
    loadrow<CPL>(xr + (size_t)wid * HC + c0, xrv);
    loadrow<CPL>(att + c0, attv);

    float m = -INFINITY, den = 0.f;
    float acc[CPL];
    #pragma unroll
    for (int q = 0; q < CPL; q++) acc[q] = 0.f;

    int p = p0 + slot;
    int s = (p < p1) ? csr_src[p] : 0;
    while (p < p1) {
        int pn = p + 4;
        int sn = (pn < p1) ? csr_src[pn] : 0;   // prefetch next index
        float xlv[CPL];
        loadrow<CPL>(xl + (size_t)s * HC + c0, xlv);
        float part = 0.f;
        #pragma unroll
        for (int q = 0; q < CPL; q++) part += lrelu(xlv[q] + xrv[q]) * attv[q];
        #pragma unroll
        for (int msk = 1; msk < GROUP; msk <<= 1) part += __shfl_xor(part, msk, 64);
        // online softmax update (per-slot private state)
        float mnew = fmaxf(m, part);
        float corr = __expf(m - mnew);   // m=-inf -> 0
        float ex = __expf(part - mnew);
        den = den * corr + ex;
        #pragma unroll
        for (int q = 0; q < CPL; q++) acc[q] = acc[q] * corr + ex * xlv[q];
        m = mnew;
        p = pn; s = sn;
    }
    // combine the 4 slots (flash-style rescale)
    float mAll = fmaxf(m, __shfl_xor(m, 16, 64));
    mAll = fmaxf(mAll, __shfl_xor(mAll, 32, 64));
    float scale = __expf(m - mAll);      // -inf slot -> 0
    float dtot = den * scale;
    dtot += __shfl_xor(dtot, 16, 64);
    dtot += __shfl_xor(dtot, 32, 64);
    #pragma unroll
    for (int q = 0; q < CPL; q++) {
        float a = acc[q] * scale;
        a += __shfl_xor(a, 16, 64);
        a += __shfl_xor(a, 32, 64);
        acc[q] = a;
    }
    if (slot == 0) {
        float inv = 1.0f / (dtot + 1e-16f);
        #pragma unroll
        for (int q = 0; q < CPL; q++) {
            float v = acc[q] * inv + bias[c0 + q];
            hout[(size_t)wid * HC + c0 + q] = elu1(v);
        }
    }
}

// ---------------- graph pooling: mean | max over sorted batch ----------------
__global__ void k_pool(const float* __restrict__ h, const int* __restrict__ batch,
                       int N, float* __restrict__ out) {
    int g = blockIdx.x;
    int lo = 0, hi = N;
    while (lo < hi) { int mid = (lo + hi) >> 1; if (batch[mid] < g) lo = mid + 1; else hi = mid; }
    int start = lo;
    lo = start; hi = N;
    while (lo < hi) { int mid = (lo + hi) >> 1; if (batch[mid] < g + 1) lo = mid + 1; else hi = mid; }
    int end = lo;

    int tid = threadIdx.x;  // 256 threads = 8 rows x 32 cols
    int col = tid & 31, row = tid >> 5;
    float sum = 0.f, mx = -INFINITY;
    for (int i = start + row; i < end; i += 8) {
        float v = h[(size_t)i * 32 + col];
        sum += v;
        mx = fmaxf(mx, v);
    }
    __shared__ float ssum[8][32], smx[8][32];
    ssum[row][col] = sum;
    smx[row][col] = mx;
    __syncthreads();
    if (tid < 32) {
        float s = 0.f, m = -INFINITY;
        #pragma unroll
        for (int r = 0; r < 8; r++) { s += ssum[r][tid]; m = fmaxf(m, smx[r][tid]); }
        int cnt = end - start;
        out[g * 64 + tid] = s / (float)cnt;
        out[g * 64 + 32 + tid] = m;
    }
}

extern "C" void kernel_launch(void* const* d_in, const int* in_sizes, int n_in,
                              void* d_out, int out_size, void* d_ws, size_t ws_size,
                              hipStream_t stream) {
    const float* x      = (const float*)d_in[0];
    const int*   ei     = (const int*)d_in[1];
    const int*   batch  = (const int*)d_in[2];
    const float* Wl1 = (const float*)d_in[3],  *bl1 = (const float*)d_in[4];
    const float* Wr1 = (const float*)d_in[5],  *br1 = (const float*)d_in[6];
    const float* att1= (const float*)d_in[7],  *b1  = (const float*)d_in[8];
    const float* Wl2 = (const float*)d_in[9],  *bl2 = (const float*)d_in[10];
    const float* Wr2 = (const float*)d_in[11], *br2 = (const float*)d_in[12];
    const float* att2= (const float*)d_in[13], *b2  = (const float*)d_in[14];
    const float* Wl3 = (const float*)d_in[15], *bl3 = (const float*)d_in[16];
    const float* Wr3 = (const float*)d_in[17], *br3 = (const float*)d_in[18];
    const float* att3= (const float*)d_in[19], *b3  = (const float*)d_in[20];

    int N = in_sizes[0] / 8;
    int E = in_sizes[1] / 2;
    int G = out_size / 64;
    int Etot = E + N;

    char* w = (char*)d_ws;
    auto carve = [&](size_t bytes) {
        void* p = (void*)w;
        w += (bytes + 255) & ~(size_t)255;
        return p;
    };
    int*   deg     = (int*)carve((size_t)N * 4);
    int*   row_off = (int*)carve((size_t)(N + 1) * 4);
    int*   cursor  = (int*)carve((size_t)N * 4);
    int*   csr_src = (int*)carve((size_t)Etot * 4);
    float* bufA    = (float*)carve((size_t)N * 128 * 4);  // xl
    float* bufB    = (float*)carve((size_t)N * 128 * 4);  // xr
    float* bufC    = (float*)carve((size_t)N * 128 * 4);  // h (layer outputs)
    (void)ws_size; (void)n_in;

    // ---- CSR by dst (incl. self loops) ----
    k_zero_i32<<<(N + 255) / 256, 256, 0, stream>>>(deg, N);
    k_hist<<<(Etot + 255) / 256, 256, 0, stream>>>(ei, E, N, deg);
    k_scan<<<1, 1024, 0, stream>>>(deg, N, row_off, cursor);
    k_scatter<<<(Etot + 255) / 256, 256, 0, stream>>>(ei, E, N, cursor, csr_src);

    int grdLin = (N + 7) / 8;
    int grdFused = (N + 3) / 4;

    // ---- Layer 1: K=8 -> 128 (H=2,C=64) ----
    k_linear<<<grdLin, 256, 8 * 8 * 4, stream>>>(x, N, 8, 128, Wl1, bl1, Wr1, br1, bufA, bufB);
    k_fused<128, 64><<<grdFused, 256, 0, stream>>>(row_off, csr_src, bufA, bufB, att1, b1, bufC, N);

    // ---- Layer 2: 128 -> 128 ----
    k_linear<<<grdLin, 256, 8 * 128 * 4, stream>>>(bufC, N, 128, 128, Wl2, bl2, Wr2, br2, bufA, bufB);
    k_fused<128, 64><<<grdFused, 256, 0, stream>>>(row_off, csr_src, bufA, bufB, att2, b2, bufC, N);

    // ---- Layer 3: 128 -> 32 (H=1,C=32) ----
    k_linear<<<grdLin, 64, 8 * 128 * 4, stream>>>(bufC, N, 128, 32, Wl3, bl3, Wr3, br3, bufA, bufB);
    k_fused<32, 32><<<grdFused, 256, 0, stream>>>(row_off, csr_src, bufA, bufB, att3, b3, bufC, N);

    // ---- pooling ----
    k_pool<<<G, 256, 0, stream>>>(bufC, batch, N, (float*)d_out);
}

// Round 3
// 604.357 us; speedup vs baseline: 1.5838x; 1.1441x over previous
//
#include <hip/hip_runtime.h>
#include <hip/hip_bf16.h>
#include <math.h>

// GATv2 3-layer GNN, MI355X. CSR-by-dst + fused online-softmax aggregation.
// R2: decomposed graph pooling (was 16-block / 0.65% occupancy, 118us).

__device__ __forceinline__ float lrelu(float x) { return x > 0.f ? x : 0.2f * x; }
__device__ __forceinline__ float elu1(float x) { return x > 0.f ? x : expm1f(x); }

// order-preserving float<->uint for atomicMax over signed floats
__device__ __forceinline__ unsigned f2ord(float x) {
    unsigned b = __float_as_uint(x);
    return (b & 0x80000000u) ? ~b : (b | 0x80000000u);
}
__device__ __forceinline__ float ord2f(unsigned u) {
    unsigned b = (u & 0x80000000u) ? (u & 0x7FFFFFFFu) : ~u;
    return __uint_as_float(b);
}

// ---------------- CSR build ----------------
__global__ void k_zero_i32(int* __restrict__ p, int n) {
    int i = blockIdx.x * blockDim.x + threadIdx.x;
    if (i < n) p[i] = 0;
}

__global__ void k_hist(const int* __restrict__ ei, int E, int N, int* __restrict__ deg) {
    int e = blockIdx.x * blockDim.x + threadIdx.x;
    int Etot = E + N;
    if (e >= Etot) return;
    int d = (e < E) ? ei[E + e] : (e - E);
    atomicAdd(&deg[d], 1);
}

__global__ void __launch_bounds__(1024) k_scan(const int* __restrict__ deg, int n,
                                               int* __restrict__ row_off, int* __restrict__ cursor) {
    __shared__ int wsum[16];
    __shared__ int sbase;
    int tid = threadIdx.x;
    int lane = tid & 63, w = tid >> 6;
    if (tid == 0) sbase = 0;
    __syncthreads();
    for (int start = 0; start < n; start += 1024) {
        int i = start + tid;
        int v = (i < n) ? deg[i] : 0;
        int s = v;
        #pragma unroll
        for (int d = 1; d < 64; d <<= 1) {
            int t = __shfl_up(s, d, 64);
            if (lane >= d) s += t;
        }
        if (lane == 63) wsum[w] = s;
        __syncthreads();
        int wbase = 0;
        for (int k = 0; k < w; k++) wbase += wsum[k];
        int excl = sbase + wbase + (s - v);
        if (i < n) { row_off[i] = excl; cursor[i] = excl; }
        __syncthreads();
        if (tid == 1023) sbase = excl + v;
        __syncthreads();
    }
    if (tid == 0) row_off[n] = sbase;
}

__global__ void k_scatter(const int* __restrict__ ei, int E, int N,
                          int* __restrict__ cursor,
                          int* __restrict__ csr_src) {
    int e = blockIdx.x * blockDim.x + threadIdx.x;
    int Etot = E + N;
    if (e >= Etot) return;
    int s, d;
    if (e < E) { s = ei[e]; d = ei[E + e]; } else { s = e - E; d = e - E; }
    int p = atomicAdd(&cursor[d], 1);
    csr_src[p] = s;
}

// ---------------- dense linear: xl = x@Wl+bl, xr = x@Wr+br ----------------
__global__ void k_linear(const float* __restrict__ x, int N, int K, int M,
                         const float* __restrict__ Wl, const float* __restrict__ bl,
                         const float* __restrict__ Wr, const float* __restrict__ br,
                         float* __restrict__ xl, float* __restrict__ xr) {
    extern __shared__ float xs[];  // [8][K]
    const int BN = 8;
    int tid = threadIdx.x;
    int base = blockIdx.x * BN;
    for (int idx = tid; idx < BN * K; idx += blockDim.x) {
        int j = idx / K, k = idx - j * K;
        int node = base + j;
        xs[idx] = (node < N) ? x[(size_t)node * K + k] : 0.f;
    }
    __syncthreads();
    bool right = (tid >= M);
    int col = right ? tid - M : tid;
    const float* W = right ? Wr : Wl;
    float b = right ? br[col] : bl[col];
    float acc[BN];
    #pragma unroll
    for (int j = 0; j < BN; j++) acc[j] = 0.f;
    for (int k = 0; k < K; k++) {
        float wv = W[(size_t)k * M + col];
        #pragma unroll
        for (int j = 0; j < BN; j++) acc[j] += xs[j * K + k] * wv;
    }
    float* out = right ? xr : xl;
    #pragma unroll
    for (int j = 0; j < BN; j++) {
        int node = base + j;
        if (node < N) out[(size_t)node * M + col] = acc[j] + b;
    }
}

// ---------------- fused online-softmax attention + aggregate ----------------
template <int CPL>
__device__ __forceinline__ void loadrow(const float* __restrict__ p, float* v) {
    if constexpr (CPL == 8) {
        float4 a = ((const float4*)p)[0];
        float4 b = ((const float4*)p)[1];
        v[0] = a.x; v[1] = a.y; v[2] = a.z; v[3] = a.w;
        v[4] = b.x; v[5] = b.y; v[6] = b.z; v[7] = b.w;
    } else {
        float2 a = ((const float2*)p)[0];
        v[0] = a.x; v[1] = a.y;
    }
}

template <int HC, int C>
__global__ void k_fused(const int* __restrict__ row_off, const int* __restrict__ csr_src,
                        const float* __restrict__ xl, const float* __restrict__ xr,
                        const float* __restrict__ att, const float* __restrict__ bias,
                        float* __restrict__ hout, int N) {
    constexpr int CPL = HC / 16;
    constexpr int GROUP = (16 * C) / HC;
    int wid = (blockIdx.x * blockDim.x + threadIdx.x) >> 6;
    int lane = threadIdx.x & 63;
    if (wid >= N) return;
    int slot = lane >> 4;
    int j = lane & 15;
    int c0 = j * CPL;

    int p0 = row_off[wid], p1 = row_off[wid + 1];

    float xrv[CPL], attv[CPL];
    loadrow<CPL>(xr + (size_t)wid * HC + c0, xrv);
    loadrow<CPL>(att + c0, attv);

    float m = -INFINITY, den = 0.f;
    float acc[CPL];
    #pragma unroll
    for (int q = 0; q < CPL; q++) acc[q] = 0.f;

    int p = p0 + slot;
    int s = (p < p1) ? csr_src[p] : 0;
    while (p < p1) {
        int pn = p + 4;
        int sn = (pn < p1) ? csr_src[pn] : 0;
        float xlv[CPL];
        loadrow<CPL>(xl + (size_t)s * HC + c0, xlv);
        float part = 0.f;
        #pragma unroll
        for (int q = 0; q < CPL; q++) part += lrelu(xlv[q] + xrv[q]) * attv[q];
        #pragma unroll
        for (int msk = 1; msk < GROUP; msk <<= 1) part += __shfl_xor(part, msk, 64);
        float mnew = fmaxf(m, part);
        float corr = __expf(m - mnew);
        float ex = __expf(part - mnew);
        den = den * corr + ex;
        #pragma unroll
        for (int q = 0; q < CPL; q++) acc[q] = acc[q] * corr + ex * xlv[q];
        m = mnew;
        p = pn; s = sn;
    }
    float mAll = fmaxf(m, __shfl_xor(m, 16, 64));
    mAll = fmaxf(mAll, __shfl_xor(mAll, 32, 64));
    float scale = __expf(m - mAll);
    float dtot = den * scale;
    dtot += __shfl_xor(dtot, 16, 64);
    dtot += __shfl_xor(dtot, 32, 64);
    #pragma unroll
    for (int q = 0; q < CPL; q++) {
        float a = acc[q] * scale;
        a += __shfl_xor(a, 16, 64);
        a += __shfl_xor(a, 32, 64);
        acc[q] = a;
    }
    if (slot == 0) {
        float inv = 1.0f / (dtot + 1e-16f);
        #pragma unroll
        for (int q = 0; q < CPL; q++) {
            float v = acc[q] * inv + bias[c0 + q];
            hout[(size_t)wid * HC + c0 + q] = elu1(v);
        }
    }
}

// ---------------- graph pooling (3-stage, parallel) ----------------
// stage 1: 256 blocks, contiguous node chunks, private run-length accum ->
//          LDS atomics -> global atomics
__global__ void __launch_bounds__(256) k_pool_partial(
        const float* __restrict__ h, const int* __restrict__ batch, int N, int G,
        float* __restrict__ gsum, unsigned* __restrict__ gmax) {
    __shared__ float lsum[512];      // [16][32]
    __shared__ unsigned lmax[512];
    int tid = threadIdx.x;
    for (int i = tid; i < G * 32; i += 256) { lsum[i] = 0.f; lmax[i] = 0u; }
    __syncthreads();
    int chunk = (N + gridDim.x - 1) / gridDim.x;
    int start = blockIdx.x * chunk;
    int end = min(N, start + chunk);
    int col = tid & 31, row = tid >> 5;
    int gc = -1; float ps = 0.f; unsigned pm = 0u;
    for (int i = start + row; i < end; i += 8) {
        int g = batch[i];
        if (g != gc) {
            if (gc >= 0) { atomicAdd(&lsum[gc * 32 + col], ps); atomicMax(&lmax[gc * 32 + col], pm); }
            gc = g; ps = 0.f; pm = 0u;
        }
        float v = h[(size_t)i * 32 + col];
        ps += v; pm = max(pm, f2ord(v));
    }
    if (gc >= 0) { atomicAdd(&lsum[gc * 32 + col], ps); atomicMax(&lmax[gc * 32 + col], pm); }
    __syncthreads();
    for (int i = tid; i < G * 32; i += 256) {
        if (lmax[i]) {  // untouched entries have lmax==0 (any real value maps >0)
            atomicAdd(&gsum[i], lsum[i]);
            atomicMax(&gmax[i], lmax[i]);
        }
    }
}

// stage 2: one block per graph, counts via binary search, write mean||max
__global__ void k_pool_final(const float* __restrict__ gsum, const unsigned* __restrict__ gmax,
                             const int* __restrict__ batch, int N, float* __restrict__ out) {
    int g = blockIdx.x;
    int t = threadIdx.x;
    __shared__ int s_cnt;
    if (t == 0) {
        int lo = 0, hi = N;
        while (lo < hi) { int m = (lo + hi) >> 1; if (batch[m] < g) lo = m + 1; else hi = m; }
        int a = lo;
        lo = a; hi = N;
        while (lo < hi) { int m = (lo + hi) >> 1; if (batch[m] < g + 1) lo = m + 1; else hi = m; }
        s_cnt = lo - a;
    }
    __syncthreads();
    if (t < 32) {
        out[g * 64 + t] = gsum[g * 32 + t] / (float)max(s_cnt, 1);
    } else {
        out[g * 64 + t] = ord2f(gmax[g * 32 + (t - 32)]);
    }
}

extern "C" void kernel_launch(void* const* d_in, const int* in_sizes, int n_in,
                              void* d_out, int out_size, void* d_ws, size_t ws_size,
                              hipStream_t stream) {
    const float* x      = (const float*)d_in[0];
    const int*   ei     = (const int*)d_in[1];
    const int*   batch  = (const int*)d_in[2];
    const float* Wl1 = (const float*)d_in[3],  *bl1 = (const float*)d_in[4];
    const float* Wr1 = (const float*)d_in[5],  *br1 = (const float*)d_in[6];
    const float* att1= (const float*)d_in[7],  *b1  = (const float*)d_in[8];
    const float* Wl2 = (const float*)d_in[9],  *bl2 = (const float*)d_in[10];
    const float* Wr2 = (const float*)d_in[11], *br2 = (const float*)d_in[12];
    const float* att2= (const float*)d_in[13], *b2  = (const float*)d_in[14];
    const float* Wl3 = (const float*)d_in[15], *bl3 = (const float*)d_in[16];
    const float* Wr3 = (const float*)d_in[17], *br3 = (const float*)d_in[18];
    const float* att3= (const float*)d_in[19], *b3  = (const float*)d_in[20];

    int N = in_sizes[0] / 8;
    int E = in_sizes[1] / 2;
    int G = out_size / 64;
    int Etot = E + N;

    char* w = (char*)d_ws;
    auto carve = [&](size_t bytes) {
        void* p = (void*)w;
        w += (bytes + 255) & ~(size_t)255;
        return p;
    };
    int*      deg     = (int*)carve((size_t)N * 4);
    int*      row_off = (int*)carve((size_t)(N + 1) * 4);
    int*      cursor  = (int*)carve((size_t)N * 4);
    int*      csr_src = (int*)carve((size_t)Etot * 4);
    float*    gsum    = (float*)carve((size_t)G * 32 * 4);
    unsigned* gmax    = (unsigned*)carve((size_t)G * 32 * 4);
    float*    bufA    = (float*)carve((size_t)N * 128 * 4);  // xl
    float*    bufB    = (float*)carve((size_t)N * 128 * 4);  // xr
    float*    bufC    = (float*)carve((size_t)N * 128 * 4);  // h (layer outputs)
    (void)ws_size; (void)n_in;

    // ---- CSR by dst (incl. self loops) + pool accumulator init ----
    k_zero_i32<<<(N + 255) / 256, 256, 0, stream>>>(deg, N);
    k_zero_i32<<<(2 * G * 32 + 255) / 256, 256, 0, stream>>>((int*)gsum, 2 * G * 32);
    k_hist<<<(Etot + 255) / 256, 256, 0, stream>>>(ei, E, N, deg);
    k_scan<<<1, 1024, 0, stream>>>(deg, N, row_off, cursor);
    k_scatter<<<(Etot + 255) / 256, 256, 0, stream>>>(ei, E, N, cursor, csr_src);

    int grdLin = (N + 7) / 8;
    int grdFused = (N + 3) / 4;

    // ---- Layer 1: K=8 -> 128 (H=2,C=64) ----
    k_linear<<<grdLin, 256, 8 * 8 * 4, stream>>>(x, N, 8, 128, Wl1, bl1, Wr1, br1, bufA, bufB);
    k_fused<128, 64><<<grdFused, 256, 0, stream>>>(row_off, csr_src, bufA, bufB, att1, b1, bufC, N);

    // ---- Layer 2: 128 -> 128 ----
    k_linear<<<grdLin, 256, 8 * 128 * 4, stream>>>(bufC, N, 128, 128, Wl2, bl2, Wr2, br2, bufA, bufB);
    k_fused<128, 64><<<grdFused, 256, 0, stream>>>(row_off, csr_src, bufA, bufB, att2, b2, bufC, N);

    // ---- Layer 3: 128 -> 32 (H=1,C=32) ----
    k_linear<<<grdLin, 64, 8 * 128 * 4, stream>>>(bufC, N, 128, 32, Wl3, bl3, Wr3, br3, bufA, bufB);
    k_fused<32, 32><<<grdFused, 256, 0, stream>>>(row_off, csr_src, bufA, bufB, att3, b3, bufC, N);

    // ---- pooling ----
    k_pool_partial<<<256, 256, 0, stream>>>(bufC, batch, N, G, gsum, gmax);
    k_pool_final<<<G, 64, 0, stream>>>(gsum, gmax, batch, N, (float*)d_out);
}

// Round 4
// 538.498 us; speedup vs baseline: 1.7775x; 1.1223x over previous
//
#include <hip/hip_runtime.h>
#include <hip/hip_bf16.h>
#include <math.h>

// GATv2 3-layer GNN, MI355X. CSR-by-dst + fused online-softmax aggregation.
// R2: decomposed graph pooling. R3: register-tiled fp32 linear (8 nodes x 4 cols/thread).

__device__ __forceinline__ float lrelu(float x) { return x > 0.f ? x : 0.2f * x; }
__device__ __forceinline__ float elu1(float x) { return x > 0.f ? x : expm1f(x); }

__device__ __forceinline__ unsigned f2ord(float x) {
    unsigned b = __float_as_uint(x);
    return (b & 0x80000000u) ? ~b : (b | 0x80000000u);
}
__device__ __forceinline__ float ord2f(unsigned u) {
    unsigned b = (u & 0x80000000u) ? (u & 0x7FFFFFFFu) : ~u;
    return __uint_as_float(b);
}

// ---------------- CSR build ----------------
__global__ void k_zero_i32(int* __restrict__ p, int n) {
    int i = blockIdx.x * blockDim.x + threadIdx.x;
    if (i < n) p[i] = 0;
}

__global__ void k_hist(const int* __restrict__ ei, int E, int N, int* __restrict__ deg) {
    int e = blockIdx.x * blockDim.x + threadIdx.x;
    int Etot = E + N;
    if (e >= Etot) return;
    int d = (e < E) ? ei[E + e] : (e - E);
    atomicAdd(&deg[d], 1);
}

__global__ void __launch_bounds__(1024) k_scan(const int* __restrict__ deg, int n,
                                               int* __restrict__ row_off, int* __restrict__ cursor) {
    __shared__ int wsum[16];
    __shared__ int sbase;
    int tid = threadIdx.x;
    int lane = tid & 63, w = tid >> 6;
    if (tid == 0) sbase = 0;
    __syncthreads();
    for (int start = 0; start < n; start += 1024) {
        int i = start + tid;
        int v = (i < n) ? deg[i] : 0;
        int s = v;
        #pragma unroll
        for (int d = 1; d < 64; d <<= 1) {
            int t = __shfl_up(s, d, 64);
            if (lane >= d) s += t;
        }
        if (lane == 63) wsum[w] = s;
        __syncthreads();
        int wbase = 0;
        for (int k = 0; k < w; k++) wbase += wsum[k];
        int excl = sbase + wbase + (s - v);
        if (i < n) { row_off[i] = excl; cursor[i] = excl; }
        __syncthreads();
        if (tid == 1023) sbase = excl + v;
        __syncthreads();
    }
    if (tid == 0) row_off[n] = sbase;
}

__global__ void k_scatter(const int* __restrict__ ei, int E, int N,
                          int* __restrict__ cursor,
                          int* __restrict__ csr_src) {
    int e = blockIdx.x * blockDim.x + threadIdx.x;
    int Etot = E + N;
    if (e >= Etot) return;
    int s, d;
    if (e < E) { s = ei[e]; d = ei[E + e]; } else { s = e - E; d = e - E; }
    int p = atomicAdd(&cursor[d], 1);
    csr_src[p] = s;
}

// ---------------- register-tiled dual linear: xl = x@Wl+bl, xr = x@Wr+br ----
// 32 nodes/block. Thread owns 8 nodes x 4 cols (32 acc). Per 4-k step:
// 8x ds_read_b128 (wave-broadcast) + 4x float4 W loads + 128 FMA (~91% density).
// K: input dim (%4==0). MH: cols per side. Block = (MH/2)*4 threads.
template <int K, int MH>
__global__ void k_linear2(const float* __restrict__ x, int N,
                          const float* __restrict__ Wl, const float* __restrict__ bl,
                          const float* __restrict__ Wr, const float* __restrict__ br,
                          float* __restrict__ xl, float* __restrict__ xr) {
    constexpr int NCG = MH / 2;       // col-groups (4 cols each) across both sides
    __shared__ float xs[32 * K];      // [node][k] row-major
    int tid = threadIdx.x;
    int node0 = blockIdx.x * 32;
    for (int idx = tid * 4; idx < 32 * K; idx += NCG * 4 * 4) {
        int node = node0 + idx / K;
        float4 v = make_float4(0.f, 0.f, 0.f, 0.f);
        if (node < N) v = *(const float4*)(x + (size_t)node0 * K + idx);
        *(float4*)(xs + idx) = v;
    }
    __syncthreads();

    int cg = tid % NCG;
    int ng = tid / NCG;
    bool rightSide = cg >= (MH / 4);
    int c = (rightSide ? cg - MH / 4 : cg) * 4;
    const float* W  = rightSide ? Wr : Wl;
    const float* bb = rightSide ? br : bl;
    float* out      = rightSide ? xr : xl;

    float acc[8][4];
    #pragma unroll
    for (int i = 0; i < 8; i++)
        #pragma unroll
        for (int j = 0; j < 4; j++) acc[i][j] = 0.f;

    const float* xrow = xs + ng * 8 * K;
    for (int k0 = 0; k0 < K; k0 += 4) {
        float4 wv[4];
        #pragma unroll
        for (int kk = 0; kk < 4; kk++)
            wv[kk] = *(const float4*)(W + (size_t)(k0 + kk) * MH + c);
        #pragma unroll
        for (int i = 0; i < 8; i++) {
            float4 xv = *(const float4*)(xrow + i * K + k0);
            float xvk[4] = {xv.x, xv.y, xv.z, xv.w};
            #pragma unroll
            for (int kk = 0; kk < 4; kk++) {
                acc[i][0] += xvk[kk] * wv[kk].x;
                acc[i][1] += xvk[kk] * wv[kk].y;
                acc[i][2] += xvk[kk] * wv[kk].z;
                acc[i][3] += xvk[kk] * wv[kk].w;
            }
        }
    }
    float4 bv = *(const float4*)(bb + c);
    #pragma unroll
    for (int i = 0; i < 8; i++) {
        int node = node0 + ng * 8 + i;
        if (node < N) {
            float4 o = make_float4(acc[i][0] + bv.x, acc[i][1] + bv.y,
                                   acc[i][2] + bv.z, acc[i][3] + bv.w);
            *(float4*)(out + (size_t)node * MH + c) = o;
        }
    }
}

// ---------------- fused online-softmax attention + aggregate ----------------
template <int CPL>
__device__ __forceinline__ void loadrow(const float* __restrict__ p, float* v) {
    if constexpr (CPL == 8) {
        float4 a = ((const float4*)p)[0];
        float4 b = ((const float4*)p)[1];
        v[0] = a.x; v[1] = a.y; v[2] = a.z; v[3] = a.w;
        v[4] = b.x; v[5] = b.y; v[6] = b.z; v[7] = b.w;
    } else {
        float2 a = ((const float2*)p)[0];
        v[0] = a.x; v[1] = a.y;
    }
}

template <int HC, int C>
__global__ void k_fused(const int* __restrict__ row_off, const int* __restrict__ csr_src,
                        const float* __restrict__ xl, const float* __restrict__ xr,
                        const float* __restrict__ att, const float* __restrict__ bias,
                        float* __restrict__ hout, int N) {
    constexpr int CPL = HC / 16;
    constexpr int GROUP = (16 * C) / HC;
    int wid = (blockIdx.x * blockDim.x + threadIdx.x) >> 6;
    int lane = threadIdx.x & 63;
    if (wid >= N) return;
    int slot = lane >> 4;
    int j = lane & 15;
    int c0 = j * CPL;

    int p0 = row_off[wid], p1 = row_off[wid + 1];

    float xrv[CPL], attv[CPL];
    loadrow<CPL>(xr + (size_t)wid * HC + c0, xrv);
    loadrow<CPL>(att + c0, attv);

    float m = -INFINITY, den = 0.f;
    float acc[CPL];
    #pragma unroll
    for (int q = 0; q < CPL; q++) acc[q] = 0.f;

    int p = p0 + slot;
    int s = (p < p1) ? csr_src[p] : 0;
    while (p < p1) {
        int pn = p + 4;
        int sn = (pn < p1) ? csr_src[pn] : 0;
        float xlv[CPL];
        loadrow<CPL>(xl + (size_t)s * HC + c0, xlv);
        float part = 0.f;
        #pragma unroll
        for (int q = 0; q < CPL; q++) part += lrelu(xlv[q] + xrv[q]) * attv[q];
        #pragma unroll
        for (int msk = 1; msk < GROUP; msk <<= 1) part += __shfl_xor(part, msk, 64);
        float mnew = fmaxf(m, part);
        float corr = __expf(m - mnew);
        float ex = __expf(part - mnew);
        den = den * corr + ex;
        #pragma unroll
        for (int q = 0; q < CPL; q++) acc[q] = acc[q] * corr + ex * xlv[q];
        m = mnew;
        p = pn; s = sn;
    }
    float mAll = fmaxf(m, __shfl_xor(m, 16, 64));
    mAll = fmaxf(mAll, __shfl_xor(mAll, 32, 64));
    float scale = __expf(m - mAll);
    float dtot = den * scale;
    dtot += __shfl_xor(dtot, 16, 64);
    dtot += __shfl_xor(dtot, 32, 64);
    #pragma unroll
    for (int q = 0; q < CPL; q++) {
        float a = acc[q] * scale;
        a += __shfl_xor(a, 16, 64);
        a += __shfl_xor(a, 32, 64);
        acc[q] = a;
    }
    if (slot == 0) {
        float inv = 1.0f / (dtot + 1e-16f);
        #pragma unroll
        for (int q = 0; q < CPL; q++) {
            float v = acc[q] * inv + bias[c0 + q];
            hout[(size_t)wid * HC + c0 + q] = elu1(v);
        }
    }
}

// ---------------- graph pooling (parallel, 2-stage) ----------------
__global__ void __launch_bounds__(256) k_pool_partial(
        const float* __restrict__ h, const int* __restrict__ batch, int N, int G,
        float* __restrict__ gsum, unsigned* __restrict__ gmax) {
    __shared__ float lsum[512];
    __shared__ unsigned lmax[512];
    int tid = threadIdx.x;
    for (int i = tid; i < G * 32; i += 256) { lsum[i] = 0.f; lmax[i] = 0u; }
    __syncthreads();
    int chunk = (N + gridDim.x - 1) / gridDim.x;
    int start = blockIdx.x * chunk;
    int end = min(N, start + chunk);
    int col = tid & 31, row = tid >> 5;
    int gc = -1; float ps = 0.f; unsigned pm = 0u;
    for (int i = start + row; i < end; i += 8) {
        int g = batch[i];
        if (g != gc) {
            if (gc >= 0) { atomicAdd(&lsum[gc * 32 + col], ps); atomicMax(&lmax[gc * 32 + col], pm); }
            gc = g; ps = 0.f; pm = 0u;
        }
        float v = h[(size_t)i * 32 + col];
        ps += v; pm = max(pm, f2ord(v));
    }
    if (gc >= 0) { atomicAdd(&lsum[gc * 32 + col], ps); atomicMax(&lmax[gc * 32 + col], pm); }
    __syncthreads();
    for (int i = tid; i < G * 32; i += 256) {
        if (lmax[i]) {
            atomicAdd(&gsum[i], lsum[i]);
            atomicMax(&gmax[i], lmax[i]);
        }
    }
}

__global__ void k_pool_final(const float* __restrict__ gsum, const unsigned* __restrict__ gmax,
                             const int* __restrict__ batch, int N, float* __restrict__ out) {
    int g = blockIdx.x;
    int t = threadIdx.x;
    __shared__ int s_cnt;
    if (t == 0) {
        int lo = 0, hi = N;
        while (lo < hi) { int m = (lo + hi) >> 1; if (batch[m] < g) lo = m + 1; else hi = m; }
        int a = lo;
        lo = a; hi = N;
        while (lo < hi) { int m = (lo + hi) >> 1; if (batch[m] < g + 1) lo = m + 1; else hi = m; }
        s_cnt = lo - a;
    }
    __syncthreads();
    if (t < 32) {
        out[g * 64 + t] = gsum[g * 32 + t] / (float)max(s_cnt, 1);
    } else {
        out[g * 64 + t] = ord2f(gmax[g * 32 + (t - 32)]);
    }
}

extern "C" void kernel_launch(void* const* d_in, const int* in_sizes, int n_in,
                              void* d_out, int out_size, void* d_ws, size_t ws_size,
                              hipStream_t stream) {
    const float* x      = (const float*)d_in[0];
    const int*   ei     = (const int*)d_in[1];
    const int*   batch  = (const int*)d_in[2];
    const float* Wl1 = (const float*)d_in[3],  *bl1 = (const float*)d_in[4];
    const float* Wr1 = (const float*)d_in[5],  *br1 = (const float*)d_in[6];
    const float* att1= (const float*)d_in[7],  *b1  = (const float*)d_in[8];
    const float* Wl2 = (const float*)d_in[9],  *bl2 = (const float*)d_in[10];
    const float* Wr2 = (const float*)d_in[11], *br2 = (const float*)d_in[12];
    const float* att2= (const float*)d_in[13], *b2  = (const float*)d_in[14];
    const float* Wl3 = (const float*)d_in[15], *bl3 = (const float*)d_in[16];
    const float* Wr3 = (const float*)d_in[17], *br3 = (const float*)d_in[18];
    const float* att3= (const float*)d_in[19], *b3  = (const float*)d_in[20];

    int N = in_sizes[0] / 8;
    int E = in_sizes[1] / 2;
    int G = out_size / 64;
    int Etot = E + N;

    char* w = (char*)d_ws;
    auto carve = [&](size_t bytes) {
        void* p = (void*)w;
        w += (bytes + 255) & ~(size_t)255;
        return p;
    };
    int*      deg     = (int*)carve((size_t)N * 4);
    int*      row_off = (int*)carve((size_t)(N + 1) * 4);
    int*      cursor  = (int*)carve((size_t)N * 4);
    int*      csr_src = (int*)carve((size_t)Etot * 4);
    float*    gsum    = (float*)carve((size_t)G * 32 * 4);
    unsigned* gmax    = (unsigned*)carve((size_t)G * 32 * 4);
    float*    bufA    = (float*)carve((size_t)N * 128 * 4);  // xl
    float*    bufB    = (float*)carve((size_t)N * 128 * 4);  // xr
    float*    bufC    = (float*)carve((size_t)N * 128 * 4);  // h (layer outputs)
    (void)ws_size; (void)n_in;

    // ---- CSR by dst (incl. self loops) + pool accumulator init ----
    k_zero_i32<<<(N + 255) / 256, 256, 0, stream>>>(deg, N);
    k_zero_i32<<<(2 * G * 32 + 255) / 256, 256, 0, stream>>>((int*)gsum, 2 * G * 32);
    k_hist<<<(Etot + 255) / 256, 256, 0, stream>>>(ei, E, N, deg);
    k_scan<<<1, 1024, 0, stream>>>(deg, N, row_off, cursor);
    k_scatter<<<(Etot + 255) / 256, 256, 0, stream>>>(ei, E, N, cursor, csr_src);

    int grdLin = (N + 31) / 32;
    int grdFused = (N + 3) / 4;

    // ---- Layer 1: K=8 -> 128 (H=2,C=64) ----
    k_linear2<8, 128><<<grdLin, 256, 0, stream>>>(x, N, Wl1, bl1, Wr1, br1, bufA, bufB);
    k_fused<128, 64><<<grdFused, 256, 0, stream>>>(row_off, csr_src, bufA, bufB, att1, b1, bufC, N);

    // ---- Layer 2: 128 -> 128 ----
    k_linear2<128, 128><<<grdLin, 256, 0, stream>>>(bufC, N, Wl2, bl2, Wr2, br2, bufA, bufB);
    k_fused<128, 64><<<grdFused, 256, 0, stream>>>(row_off, csr_src, bufA, bufB, att2, b2, bufC, N);

    // ---- Layer 3: 128 -> 32 (H=1,C=32) ----
    k_linear2<128, 32><<<grdLin, 64, 0, stream>>>(bufC, N, Wl3, bl3, Wr3, br3, bufA, bufB);
    k_fused<32, 32><<<grdFused, 256, 0, stream>>>(row_off, csr_src, bufA, bufB, att3, b3, bufC, N);

    // ---- pooling ----
    k_pool_partial<<<256, 256, 0, stream>>>(bufC, batch, N, G, gsum, gmax);
    k_pool_final<<<G, 64, 0, stream>>>(gsum, gmax, batch, N, (float*)d_out);
}